// Round 4
// baseline (476.210 us; speedup 1.0000x reference)
//
#include <hip/hip_runtime.h>

#define EPS 1e-5f

typedef unsigned short u16;
typedef __attribute__((ext_vector_type(8))) __bf16 bf16x8;
typedef __attribute__((ext_vector_type(4))) float f32x4;
typedef __attribute__((ext_vector_type(8))) unsigned short ushort8;

__device__ inline float bf2f(u16 h) {
  union { unsigned u; float f; } x; x.u = ((unsigned)h) << 16; return x.f;
}
__device__ inline u16 f2bf(float f) {
  union { float f; unsigned u; } x; x.f = f;
  unsigned r = x.u + 0x7fffu + ((x.u >> 16) & 1u);
  return (u16)(r >> 16);
}
__device__ inline float sigmoidf(float x) { return 1.0f / (1.0f + __expf(-x)); }

// ---------------- cast: 4 equal-size f32 -> bf16(u16) arrays ----------------
__global__ __launch_bounds__(256) void cast4_f32_bf16(
    const float* __restrict__ s0, const float* __restrict__ s1,
    const float* __restrict__ s2, const float* __restrict__ s3,
    u16* __restrict__ d0, u16* __restrict__ d1,
    u16* __restrict__ d2, u16* __restrict__ d3, int n)
{
  const float* s = (blockIdx.y == 0) ? s0 : (blockIdx.y == 1) ? s1 : (blockIdx.y == 2) ? s2 : s3;
  u16*         d = (blockIdx.y == 0) ? d0 : (blockIdx.y == 1) ? d1 : (blockIdx.y == 2) ? d2 : d3;
  int i = (blockIdx.x * 256 + threadIdx.x) * 8;
  if (i >= n) return;
  float4 a = *(const float4*)(s + i);
  float4 b = *(const float4*)(s + i + 4);
  ushort8 o;
  o[0] = f2bf(a.x); o[1] = f2bf(a.y); o[2] = f2bf(a.z); o[3] = f2bf(a.w);
  o[4] = f2bf(b.x); o[5] = f2bf(b.y); o[6] = f2bf(b.z); o[7] = f2bf(b.w);
  *(ushort8*)(d + i) = o;
}

// ---------------- GEMM: C[m][n] = sum_k A[m][k] * W[n][k] -------------------
// 256x256 tile, BK=32, 512 threads (8 waves, 2Mx4N), 64 KiB LDS double-buffer
// -> 2 blocks/CU (TLP covers vmcnt/lgkm/barrier stalls; m97/m114 mechanism).
// T4: counted vmcnt(4) only; 1 tile prefetch in flight; last tile peeled.
// T2: LDS 16B-slot swizzle slot' = k8 ^ (row&3) ^ ((row>>2)&3), staged via
// pre-swizzled GLOBAL source + linear global_load_lds dest (rule 21).
// T1: bijective XCD swizzle (512 % 8 == 0).
#define MFMA_ __builtin_amdgcn_mfma_f32_16x16x32_bf16

// stage one tile (A+B) into buffer nx at k-offset kt: 4 gload_lds per thread
#define STAGE(nx, kt) { \
  _Pragma("unroll") for (int i_ = 0; i_ < 2; ++i_) \
    __builtin_amdgcn_global_load_lds( \
        (const __attribute__((address_space(1))) void*)(gA + (size_t)(i_ * 128) * K + (kt)), \
        (__attribute__((address_space(3))) void*)(&sA[nx][(i_ * 512 + tid) * 8]), 16, 0, 0); \
  _Pragma("unroll") for (int i_ = 0; i_ < 2; ++i_) \
    __builtin_amdgcn_global_load_lds( \
        (const __attribute__((address_space(1))) void*)(gB + (size_t)(i_ * 128) * K + (kt)), \
        (__attribute__((address_space(3))) void*)(&sB[nx][(i_ * 512 + tid) * 8]), 16, 0, 0); }

#define LDA(mi) (*(const bf16x8*)&sa[(arow + (mi) * 16) * 32 + slr])
#define LDB(ni) (*(const bf16x8*)&sb[(brow + (ni) * 16) * 32 + slr])

#define MFMA16(m0, a0, a1, a2, a3) \
  __builtin_amdgcn_s_setprio(1); \
  acc[m0 + 0][0] = MFMA_(a0, q0, acc[m0 + 0][0], 0, 0, 0); \
  acc[m0 + 0][1] = MFMA_(a0, q1, acc[m0 + 0][1], 0, 0, 0); \
  acc[m0 + 0][2] = MFMA_(a0, q2, acc[m0 + 0][2], 0, 0, 0); \
  acc[m0 + 0][3] = MFMA_(a0, q3, acc[m0 + 0][3], 0, 0, 0); \
  acc[m0 + 1][0] = MFMA_(a1, q0, acc[m0 + 1][0], 0, 0, 0); \
  acc[m0 + 1][1] = MFMA_(a1, q1, acc[m0 + 1][1], 0, 0, 0); \
  acc[m0 + 1][2] = MFMA_(a1, q2, acc[m0 + 1][2], 0, 0, 0); \
  acc[m0 + 1][3] = MFMA_(a1, q3, acc[m0 + 1][3], 0, 0, 0); \
  acc[m0 + 2][0] = MFMA_(a2, q0, acc[m0 + 2][0], 0, 0, 0); \
  acc[m0 + 2][1] = MFMA_(a2, q1, acc[m0 + 2][1], 0, 0, 0); \
  acc[m0 + 2][2] = MFMA_(a2, q2, acc[m0 + 2][2], 0, 0, 0); \
  acc[m0 + 2][3] = MFMA_(a2, q3, acc[m0 + 2][3], 0, 0, 0); \
  acc[m0 + 3][0] = MFMA_(a3, q0, acc[m0 + 3][0], 0, 0, 0); \
  acc[m0 + 3][1] = MFMA_(a3, q1, acc[m0 + 3][1], 0, 0, 0); \
  acc[m0 + 3][2] = MFMA_(a3, q2, acc[m0 + 3][2], 0, 0, 0); \
  acc[m0 + 3][3] = MFMA_(a3, q3, acc[m0 + 3][3], 0, 0, 0); \
  __builtin_amdgcn_s_setprio(0);

// one K-tile of compute: 2 phases of 16 MFMA, 1 internal barrier
#define TILE_COMPUTE(sa, sb) { \
  bf16x8 a0 = LDA(0), a1 = LDA(1), a2 = LDA(2), a3 = LDA(3); \
  q0 = LDB(0); q1 = LDB(1); q2 = LDB(2); q3 = LDB(3); \
  MFMA16(0, a0, a1, a2, a3) \
  bf16x8 a4 = LDA(4), a5 = LDA(5), a6 = LDA(6), a7 = LDA(7); \
  __builtin_amdgcn_s_barrier(); \
  MFMA16(4, a4, a5, a6, a7) }

__global__ __launch_bounds__(512, 4) void gemm256_dual(
    const u16* __restrict__ A0, const u16* __restrict__ W0, u16* __restrict__ C0,
    const u16* __restrict__ A1, const u16* __restrict__ W1, u16* __restrict__ C1)
{
  constexpr int K = 1024, N = 4096, NT = 32;  // K-tiles of 32

  __shared__ __attribute__((aligned(16))) u16 sA[2][256 * 32];  // 2 x 16 KiB
  __shared__ __attribute__((aligned(16))) u16 sB[2][256 * 32];  // 2 x 16 KiB

  // T1: bijective XCD swizzle (512 blocks % 8 XCDs == 0)
  const int b0  = blockIdx.x;
  const int bid = (b0 & 7) * 64 + (b0 >> 3);

  const u16* A  = (bid < 256) ? A0 : A1;
  const u16* Wm = (bid < 256) ? W0 : W1;
  u16*       C  = (bid < 256) ? C0 : C1;
  const int b2 = bid & 255;
  const int bm = (b2 >> 4) << 8;
  const int bn = (b2 & 15) << 8;

  const int tid = threadIdx.x;
  const int l  = tid & 63;
  const int w  = tid >> 6;   // wave 0..7
  const int wr = w >> 2;     // 0..1  -> M offset wr*128
  const int wc = w & 3;      // 0..3  -> N offset wc*64

  // staging: thread tid stages chunks c = i*512+tid (i=0,1), 16B each.
  // LDS linear: byte c*16 -> row c>>2 (= i*128 + (tid>>2)), slot tid&3.
  // global source slot pre-swizzled: k8_src = (tid&3) ^ (row&3) ^ ((row>>2)&3);
  // both swizzle terms are invariant across i (row step 128).
  const int r0  = tid >> 2;
  const int ssw = ((tid >> 2) & 3) ^ ((tid >> 4) & 3);
  const int soff = ((tid & 3) ^ ssw) * 8;
  const u16* gA = A  + (size_t)(bm + r0) * K + soff;
  const u16* gB = Wm + (size_t)(bn + r0) * K + soff;

  // fragment reads: row = base + mi*16 + (l&15), k8 = l>>4;
  // slot = (k8 ^ (row&3) ^ ((row>>2)&3)) -- both row terms reduce to lane bits
  const int arow = wr * 128 + (l & 15);
  const int brow = wc * 64 + (l & 15);
  const int slr = (((l >> 4) ^ (l & 3) ^ ((l >> 2) & 3))) * 8;

  f32x4 acc[8][4];
#pragma unroll
  for (int i = 0; i < 8; ++i)
#pragma unroll
    for (int j = 0; j < 4; ++j) acc[i][j] = (f32x4){0.f, 0.f, 0.f, 0.f};

  // prologue: stage K-tile 0 into buffer 0 (4 loads in flight, NO drain)
  STAGE(0, 0)

  for (int t = 0; t < NT - 1; ++t) {
    const int cur = t & 1, nxt = cur ^ 1;
    const u16* sa = sA[cur];
    const u16* sb = sB[cur];
    bf16x8 q0, q1, q2, q3;

    STAGE(nxt, (t + 1) * 32)                          // outstanding: 4 + 4
    asm volatile("s_waitcnt vmcnt(4)" ::: "memory");  // tile t landed; t+1 in flight
    __builtin_amdgcn_s_barrier();
    TILE_COMPUTE(sa, sb)
    // no drain: next iter's vmcnt(4)+barrier orders buffer reuse; all waves'
    // reads of buf[nxt] were issued before the internal barrier of iter t-1.
  }

  {  // peeled last tile
    const u16* sa = sA[(NT - 1) & 1];
    const u16* sb = sB[(NT - 1) & 1];
    bf16x8 q0, q1, q2, q3;
    asm volatile("s_waitcnt vmcnt(0)" ::: "memory");
    __builtin_amdgcn_s_barrier();
    TILE_COMPUTE(sa, sb)
  }

  // C write: col = lane&15, row = (lane>>4)*4 + reg  (m89/m91-verified layout)
  const int ccol = bn + wc * 64 + (l & 15);
  const int crow = bm + wr * 128 + (l >> 4) * 4;
#pragma unroll
  for (int mi = 0; mi < 8; ++mi) {
#pragma unroll
    for (int ni = 0; ni < 4; ++ni) {
      int col = ccol + ni * 16;
#pragma unroll
      for (int r = 0; r < 4; ++r) {
        int row = crow + mi * 16 + r;
        C[(size_t)row * N + col] = f2bf(acc[mi][ni][r]);
      }
    }
  }
}

// ---------------- fused LN(ig) + LN(hg) + gates + cell-LN + outputs ----------
__global__ __launch_bounds__(256) void lstm_epilogue(
    const u16* __restrict__ ig, const u16* __restrict__ hg,
    const float* __restrict__ cx,
    const float* __restrict__ gi, const float* __restrict__ bi,
    const float* __restrict__ gh, const float* __restrict__ bh,
    const float* __restrict__ gc, const float* __restrict__ bc,
    float* __restrict__ out)
{
  const int b = blockIdx.x;
  const int t = threadIdx.x;
  const u16* igr = ig + (size_t)b * 4096;
  const u16* hgr = hg + (size_t)b * 4096;

  __shared__ float redbuf[16];

  float iv[16], hv[16];
  float s_i = 0.f, q_i = 0.f, s_h = 0.f, q_h = 0.f;
#pragma unroll
  for (int i = 0; i < 16; ++i) {
    float a = bf2f(igr[t + 256 * i]);
    float c = bf2f(hgr[t + 256 * i]);
    iv[i] = a; hv[i] = c;
    s_i += a; q_i += a * a; s_h += c; q_h += c * c;
  }
#pragma unroll
  for (int off = 32; off > 0; off >>= 1) {
    s_i += __shfl_xor(s_i, off);
    q_i += __shfl_xor(q_i, off);
    s_h += __shfl_xor(s_h, off);
    q_h += __shfl_xor(q_h, off);
  }
  {
    int wv = t >> 6;
    if ((t & 63) == 0) {
      redbuf[wv] = s_i; redbuf[wv + 4] = q_i;
      redbuf[wv + 8] = s_h; redbuf[wv + 12] = q_h;
    }
    __syncthreads();
    s_i = redbuf[0] + redbuf[1] + redbuf[2] + redbuf[3];
    q_i = redbuf[4] + redbuf[5] + redbuf[6] + redbuf[7];
    s_h = redbuf[8] + redbuf[9] + redbuf[10] + redbuf[11];
    q_h = redbuf[12] + redbuf[13] + redbuf[14] + redbuf[15];
    __syncthreads();
  }
  const float inv4096 = 1.0f / 4096.0f;
  float mu_i = s_i * inv4096;
  float rs_i = rsqrtf(q_i * inv4096 - mu_i * mu_i + EPS);
  float mu_h = s_h * inv4096;
  float rs_h = rsqrtf(q_h * inv4096 - mu_h * mu_h + EPS);

  float c_pre[4], og[4];
  float s_c = 0.f, q_c = 0.f;
#pragma unroll
  for (int i = 0; i < 4; ++i) {
    int h = t + 256 * i;
    float g_in = ((iv[i]      - mu_i) * rs_i * gi[h]        + bi[h]) +
                 ((hv[i]      - mu_h) * rs_h * gh[h]        + bh[h]);
    float g_fg = ((iv[i + 4]  - mu_i) * rs_i * gi[h + 1024] + bi[h + 1024]) +
                 ((hv[i + 4]  - mu_h) * rs_h * gh[h + 1024] + bh[h + 1024]);
    float g_cl = ((iv[i + 8]  - mu_i) * rs_i * gi[h + 2048] + bi[h + 2048]) +
                 ((hv[i + 8]  - mu_h) * rs_h * gh[h + 2048] + bh[h + 2048]);
    float g_og = ((iv[i + 12] - mu_i) * rs_i * gi[h + 3072] + bi[h + 3072]) +
                 ((hv[i + 12] - mu_h) * rs_h * gh[h + 3072] + bh[h + 3072]);
    float in_s = sigmoidf(g_in);
    float fg_s = sigmoidf(g_fg);
    float cl_t = tanhf(g_cl);
    og[i] = sigmoidf(g_og);
    c_pre[i] = fg_s * cx[(size_t)b * 1024 + h] + in_s * cl_t;
    s_c += c_pre[i]; q_c += c_pre[i] * c_pre[i];
  }
#pragma unroll
  for (int off = 32; off > 0; off >>= 1) {
    s_c += __shfl_xor(s_c, off);
    q_c += __shfl_xor(q_c, off);
  }
  {
    int wv = t >> 6;
    if ((t & 63) == 0) { redbuf[wv] = s_c; redbuf[wv + 4] = q_c; }
    __syncthreads();
    s_c = redbuf[0] + redbuf[1] + redbuf[2] + redbuf[3];
    q_c = redbuf[4] + redbuf[5] + redbuf[6] + redbuf[7];
  }
  const float inv1024 = 1.0f / 1024.0f;
  float mu_c = s_c * inv1024;
  float rs_c = rsqrtf(q_c * inv1024 - mu_c * mu_c + EPS);

  const size_t BH = (size_t)4096 * 1024;
#pragma unroll
  for (int i = 0; i < 4; ++i) {
    int h = t + 256 * i;
    float cy = (c_pre[i] - mu_c) * rs_c * gc[h] + bc[h];
    float hy = og[i] * tanhf(cy);
    size_t o = (size_t)b * 1024 + h;
    out[o] = hy;
    out[BH + o] = hy;
    out[2 * BH + o] = cy;
  }
}

extern "C" void kernel_launch(void* const* d_in, const int* in_sizes, int n_in,
                              void* d_out, int out_size, void* d_ws, size_t ws_size,
                              hipStream_t stream) {
  const float* input = (const float*)d_in[0];
  const float* hx    = (const float*)d_in[1];
  const float* cx    = (const float*)d_in[2];
  const float* wih   = (const float*)d_in[3];
  const float* whh   = (const float*)d_in[4];
  const float* gi    = (const float*)d_in[5];
  const float* bi    = (const float*)d_in[6];
  const float* gh    = (const float*)d_in[7];
  const float* bh    = (const float*)d_in[8];
  const float* gc    = (const float*)d_in[9];
  const float* bc    = (const float*)d_in[10];
  float* out = (float*)d_out;

  char* wsp = (char*)d_ws;
  u16* a_bf  = (u16*)(wsp);
  u16* h_bf  = (u16*)(wsp + ((size_t)8  << 20));
  u16* wi_bf = (u16*)(wsp + ((size_t)16 << 20));
  u16* wh_bf = (u16*)(wsp + ((size_t)24 << 20));
  u16* ig_bf = (u16*)(wsp + ((size_t)32 << 20));
  u16* hg_bf = (u16*)(wsp + ((size_t)64 << 20));

  const int nper = 4096 * 1024;
  dim3 cgrid(nper / 8 / 256, 4);
  cast4_f32_bf16<<<cgrid, 256, 0, stream>>>(input, hx, wih, whh,
                                            a_bf, h_bf, wi_bf, wh_bf, nper);

  gemm256_dual<<<512, 512, 0, stream>>>(a_bf, wi_bf, ig_bf,
                                        h_bf, wh_bf, hg_bf);

  lstm_epilogue<<<4096, 256, 0, stream>>>(ig_bf, hg_bf, cx,
                                          gi, bi, gh, bh, gc, bc, out);
}

// Round 5
// 125.021 us; speedup vs baseline: 3.8090x; 3.8090x over previous
//
#include <hip/hip_runtime.h>

#define EPS 1e-5f

typedef unsigned short u16;
typedef __attribute__((ext_vector_type(8))) __bf16 bf16x8;
typedef __attribute__((ext_vector_type(4))) float f32x4;
typedef __attribute__((ext_vector_type(8))) unsigned short ushort8;

__device__ inline float bf2f(u16 h) {
  union { unsigned u; float f; } x; x.u = ((unsigned)h) << 16; return x.f;
}
__device__ inline u16 f2bf(float f) {
  union { float f; unsigned u; } x; x.f = f;
  unsigned r = x.u + 0x7fffu + ((x.u >> 16) & 1u);
  return (u16)(r >> 16);
}
__device__ inline float sigmoidf(float x) { return 1.0f / (1.0f + __expf(-x)); }

// ---------------- cast: 4 equal-size f32 -> bf16(u16) arrays ----------------
__global__ __launch_bounds__(256) void cast4_f32_bf16(
    const float* __restrict__ s0, const float* __restrict__ s1,
    const float* __restrict__ s2, const float* __restrict__ s3,
    u16* __restrict__ d0, u16* __restrict__ d1,
    u16* __restrict__ d2, u16* __restrict__ d3, int n)
{
  const float* s = (blockIdx.y == 0) ? s0 : (blockIdx.y == 1) ? s1 : (blockIdx.y == 2) ? s2 : s3;
  u16*         d = (blockIdx.y == 0) ? d0 : (blockIdx.y == 1) ? d1 : (blockIdx.y == 2) ? d2 : d3;
  int i = (blockIdx.x * 256 + threadIdx.x) * 8;
  if (i >= n) return;
  float4 a = *(const float4*)(s + i);
  float4 b = *(const float4*)(s + i + 4);
  ushort8 o;
  o[0] = f2bf(a.x); o[1] = f2bf(a.y); o[2] = f2bf(a.z); o[3] = f2bf(a.w);
  o[4] = f2bf(b.x); o[5] = f2bf(b.y); o[6] = f2bf(b.z); o[7] = f2bf(b.w);
  *(ushort8*)(d + i) = o;
}

// ---------------- GEMM: C[m][n] = sum_k A[m][k] * W[n][k] -------------------
// 256x256 tile, BK=64, 512 threads (8 waves, 2Mx4N), 128 KiB LDS dbuf,
// 1 block/CU. Template-faithful phases (m201): per phase {ds_reads; stage;
// barrier; setprio(1) 16 MFMA setprio(0); barrier} -- the TRAILING barrier
// staggers waves so DS-pipe and matrix-pipe overlap across waves instead of
// lockstep-bursting. Phase p = mi-pair {2p,2p+1} x ni0-3 x full K=64; all 8
// B-frags hoisted to regs at phase 1. T4: counted vmcnt(4) only, last tile
// peeled with vmcnt(0). T2 swizzle + T1 XCD swizzle as verified in R2/R3.
#define MFMA_ __builtin_amdgcn_mfma_f32_16x16x32_bf16

#define STAGE_A(nx, kt) { _Pragma("unroll") for (int i_ = 0; i_ < 4; ++i_) \
  __builtin_amdgcn_global_load_lds( \
      (const __attribute__((address_space(1))) void*)(gA + (size_t)(i_ * 64) * K + (kt)), \
      (__attribute__((address_space(3))) void*)(&sA[nx][(i_ * 512 + (w << 6)) * 8]), 16, 0, 0); }

#define STAGE_B_H(nx, kt, h) { _Pragma("unroll") for (int i_ = 2*(h); i_ < 2*(h)+2; ++i_) \
  __builtin_amdgcn_global_load_lds( \
      (const __attribute__((address_space(1))) void*)(gB + (size_t)(i_ * 64) * K + (kt)), \
      (__attribute__((address_space(3))) void*)(&sB[nx][(i_ * 512 + (w << 6)) * 8]), 16, 0, 0); }

#define LDA_(mi, sl) (*(const bf16x8*)&sa[(arow + (mi) * 16) * 64 + (sl)])
#define LDB_(ni, sl) (*(const bf16x8*)&sb[(brow + (ni) * 16) * 64 + (sl)])

#define PH_TOPQ(m0) \
  q00 = LDB_(0, sl0); q01 = LDB_(1, sl0); q02 = LDB_(2, sl0); q03 = LDB_(3, sl0); \
  q10 = LDB_(0, sl1); q11 = LDB_(1, sl1); q12 = LDB_(2, sl1); q13 = LDB_(3, sl1); \
  x0 = LDA_(m0, sl0); x1 = LDA_(m0, sl1); x2 = LDA_(m0 + 1, sl0); x3 = LDA_(m0 + 1, sl1);

#define PH_TOPA(m0) \
  x0 = LDA_(m0, sl0); x1 = LDA_(m0, sl1); x2 = LDA_(m0 + 1, sl0); x3 = LDA_(m0 + 1, sl1);

#define PH_BOT(m0) \
  __builtin_amdgcn_s_barrier(); \
  __builtin_amdgcn_s_setprio(1); \
  acc[m0 + 0][0] = MFMA_(x0, q00, acc[m0 + 0][0], 0, 0, 0); \
  acc[m0 + 0][1] = MFMA_(x0, q01, acc[m0 + 0][1], 0, 0, 0); \
  acc[m0 + 0][2] = MFMA_(x0, q02, acc[m0 + 0][2], 0, 0, 0); \
  acc[m0 + 0][3] = MFMA_(x0, q03, acc[m0 + 0][3], 0, 0, 0); \
  acc[m0 + 1][0] = MFMA_(x2, q00, acc[m0 + 1][0], 0, 0, 0); \
  acc[m0 + 1][1] = MFMA_(x2, q01, acc[m0 + 1][1], 0, 0, 0); \
  acc[m0 + 1][2] = MFMA_(x2, q02, acc[m0 + 1][2], 0, 0, 0); \
  acc[m0 + 1][3] = MFMA_(x2, q03, acc[m0 + 1][3], 0, 0, 0); \
  acc[m0 + 0][0] = MFMA_(x1, q10, acc[m0 + 0][0], 0, 0, 0); \
  acc[m0 + 0][1] = MFMA_(x1, q11, acc[m0 + 0][1], 0, 0, 0); \
  acc[m0 + 0][2] = MFMA_(x1, q12, acc[m0 + 0][2], 0, 0, 0); \
  acc[m0 + 0][3] = MFMA_(x1, q13, acc[m0 + 0][3], 0, 0, 0); \
  acc[m0 + 1][0] = MFMA_(x3, q10, acc[m0 + 1][0], 0, 0, 0); \
  acc[m0 + 1][1] = MFMA_(x3, q11, acc[m0 + 1][1], 0, 0, 0); \
  acc[m0 + 1][2] = MFMA_(x3, q12, acc[m0 + 1][2], 0, 0, 0); \
  acc[m0 + 1][3] = MFMA_(x3, q13, acc[m0 + 1][3], 0, 0, 0); \
  __builtin_amdgcn_s_setprio(0); \
  __builtin_amdgcn_s_barrier();

__global__ __launch_bounds__(512, 2) void gemm256_dual(
    const u16* __restrict__ A0, const u16* __restrict__ W0, u16* __restrict__ C0,
    const u16* __restrict__ A1, const u16* __restrict__ W1, u16* __restrict__ C1)
{
  constexpr int K = 1024, N = 4096, NT = 16;  // K-tiles of 64

  __shared__ __attribute__((aligned(16))) u16 sA[2][256 * 64];  // 2 x 32 KiB
  __shared__ __attribute__((aligned(16))) u16 sB[2][256 * 64];  // 2 x 32 KiB

  // T1: bijective XCD swizzle (512 blocks % 8 XCDs == 0)
  const int b0  = blockIdx.x;
  const int bid = (b0 & 7) * 64 + (b0 >> 3);

  const u16* A  = (bid < 256) ? A0 : A1;
  const u16* Wm = (bid < 256) ? W0 : W1;
  u16*       C  = (bid < 256) ? C0 : C1;
  const int b2 = bid & 255;
  const int bm = (b2 >> 4) << 8;
  const int bn = (b2 & 15) << 8;

  const int tid = threadIdx.x;
  const int l  = tid & 63;
  const int w  = tid >> 6;   // wave 0..7
  const int wr = w >> 2;     // 0..1  -> M offset wr*128
  const int wc = w & 3;      // 0..3  -> N offset wc*64

  // staging: thread tid, chunk i -> LDS row i*64 + (tid>>3), slot tid&7 (linear);
  // global source column pre-swizzled: k8_src = (tid&7) ^ (row&7)
  const int rb   = tid >> 3;
  const int slot = (tid & 7) ^ (rb & 7);
  const u16* gA = A  + (size_t)(bm + rb) * K + slot * 8;
  const u16* gB = Wm + (size_t)(bn + rb) * K + slot * 8;

  // fragment read addressing (swizzled): elem = row*64 + ((k8 ^ (row&7))*8)
  const int arow = wr * 128 + (l & 15);
  const int brow = wc * 64 + (l & 15);
  const int sl0 = (((l >> 4) + 0) ^ (l & 7)) * 8;  // ks=0: k8 = l>>4
  const int sl1 = (((l >> 4) + 4) ^ (l & 7)) * 8;  // ks=1: k8 = 4 + (l>>4)

  f32x4 acc[8][4];
#pragma unroll
  for (int i = 0; i < 8; ++i)
#pragma unroll
    for (int j = 0; j < 4; ++j) acc[i][j] = (f32x4){0.f, 0.f, 0.f, 0.f};

  // prologue: stage K-tile 0 into buffer 0 (8 loads in flight, NO drain)
  STAGE_A(0, 0)
  STAGE_B_H(0, 0, 0)
  STAGE_B_H(0, 0, 1)

  for (int t = 0; t < NT - 1; ++t) {
    const int cur = t & 1, nxt = cur ^ 1;
    const int kn = (t + 1) << 6;
    const u16* sa = sA[cur];
    const u16* sb = sB[cur];
    bf16x8 q00, q01, q02, q03, q10, q11, q12, q13, x0, x1, x2, x3;

    STAGE_A(nxt, kn)                                  // outstanding: 8 + 4
    asm volatile("s_waitcnt vmcnt(4)" ::: "memory");  // tile t landed; A(t+1) in flight
    __builtin_amdgcn_s_barrier();
    PH_TOPQ(0)                                        // 8 B-frags + A mi0,1
    STAGE_B_H(nxt, kn, 0)
    PH_BOT(0)
    PH_TOPA(2)
    STAGE_B_H(nxt, kn, 1)
    PH_BOT(2)
    PH_TOPA(4)
    PH_BOT(4)
    PH_TOPA(6)
    PH_BOT(6)
    // no drain: next iter's vmcnt(4)+barrier orders buffer reuse
  }

  {  // peeled last tile (t = NT-1): nothing left to prefetch
    const u16* sa = sA[(NT - 1) & 1];
    const u16* sb = sB[(NT - 1) & 1];
    bf16x8 q00, q01, q02, q03, q10, q11, q12, q13, x0, x1, x2, x3;
    asm volatile("s_waitcnt vmcnt(0)" ::: "memory");
    __builtin_amdgcn_s_barrier();
    PH_TOPQ(0)
    PH_BOT(0)
    PH_TOPA(2)
    PH_BOT(2)
    PH_TOPA(4)
    PH_BOT(4)
    PH_TOPA(6)
    PH_BOT(6)
  }

  // C write: col = lane&15, row = (lane>>4)*4 + reg  (m89/m91-verified layout)
  const int ccol = bn + wc * 64 + (l & 15);
  const int crow = bm + wr * 128 + (l >> 4) * 4;
#pragma unroll
  for (int mi = 0; mi < 8; ++mi) {
#pragma unroll
    for (int ni = 0; ni < 4; ++ni) {
      int col = ccol + ni * 16;
#pragma unroll
      for (int r = 0; r < 4; ++r) {
        int row = crow + mi * 16 + r;
        C[(size_t)row * N + col] = f2bf(acc[mi][ni][r]);
      }
    }
  }
}

// ---------------- fused LN(ig) + LN(hg) + gates + cell-LN + outputs ----------
__global__ __launch_bounds__(256) void lstm_epilogue(
    const u16* __restrict__ ig, const u16* __restrict__ hg,
    const float* __restrict__ cx,
    const float* __restrict__ gi, const float* __restrict__ bi,
    const float* __restrict__ gh, const float* __restrict__ bh,
    const float* __restrict__ gc, const float* __restrict__ bc,
    float* __restrict__ out)
{
  const int b = blockIdx.x;
  const int t = threadIdx.x;
  const u16* igr = ig + (size_t)b * 4096;
  const u16* hgr = hg + (size_t)b * 4096;

  __shared__ float redbuf[16];

  float iv[16], hv[16];
  float s_i = 0.f, q_i = 0.f, s_h = 0.f, q_h = 0.f;
#pragma unroll
  for (int i = 0; i < 16; ++i) {
    float a = bf2f(igr[t + 256 * i]);
    float c = bf2f(hgr[t + 256 * i]);
    iv[i] = a; hv[i] = c;
    s_i += a; q_i += a * a; s_h += c; q_h += c * c;
  }
#pragma unroll
  for (int off = 32; off > 0; off >>= 1) {
    s_i += __shfl_xor(s_i, off);
    q_i += __shfl_xor(q_i, off);
    s_h += __shfl_xor(s_h, off);
    q_h += __shfl_xor(q_h, off);
  }
  {
    int wv = t >> 6;
    if ((t & 63) == 0) {
      redbuf[wv] = s_i; redbuf[wv + 4] = q_i;
      redbuf[wv + 8] = s_h; redbuf[wv + 12] = q_h;
    }
    __syncthreads();
    s_i = redbuf[0] + redbuf[1] + redbuf[2] + redbuf[3];
    q_i = redbuf[4] + redbuf[5] + redbuf[6] + redbuf[7];
    s_h = redbuf[8] + redbuf[9] + redbuf[10] + redbuf[11];
    q_h = redbuf[12] + redbuf[13] + redbuf[14] + redbuf[15];
    __syncthreads();
  }
  const float inv4096 = 1.0f / 4096.0f;
  float mu_i = s_i * inv4096;
  float rs_i = rsqrtf(q_i * inv4096 - mu_i * mu_i + EPS);
  float mu_h = s_h * inv4096;
  float rs_h = rsqrtf(q_h * inv4096 - mu_h * mu_h + EPS);

  float c_pre[4], og[4];
  float s_c = 0.f, q_c = 0.f;
#pragma unroll
  for (int i = 0; i < 4; ++i) {
    int h = t + 256 * i;
    float g_in = ((iv[i]      - mu_i) * rs_i * gi[h]        + bi[h]) +
                 ((hv[i]      - mu_h) * rs_h * gh[h]        + bh[h]);
    float g_fg = ((iv[i + 4]  - mu_i) * rs_i * gi[h + 1024] + bi[h + 1024]) +
                 ((hv[i + 4]  - mu_h) * rs_h * gh[h + 1024] + bh[h + 1024]);
    float g_cl = ((iv[i + 8]  - mu_i) * rs_i * gi[h + 2048] + bi[h + 2048]) +
                 ((hv[i + 8]  - mu_h) * rs_h * gh[h + 2048] + bh[h + 2048]);
    float g_og = ((iv[i + 12] - mu_i) * rs_i * gi[h + 3072] + bi[h + 3072]) +
                 ((hv[i + 12] - mu_h) * rs_h * gh[h + 3072] + bh[h + 3072]);
    float in_s = sigmoidf(g_in);
    float fg_s = sigmoidf(g_fg);
    float cl_t = tanhf(g_cl);
    og[i] = sigmoidf(g_og);
    c_pre[i] = fg_s * cx[(size_t)b * 1024 + h] + in_s * cl_t;
    s_c += c_pre[i]; q_c += c_pre[i] * c_pre[i];
  }
#pragma unroll
  for (int off = 32; off > 0; off >>= 1) {
    s_c += __shfl_xor(s_c, off);
    q_c += __shfl_xor(q_c, off);
  }
  {
    int wv = t >> 6;
    if ((t & 63) == 0) { redbuf[wv] = s_c; redbuf[wv + 4] = q_c; }
    __syncthreads();
    s_c = redbuf[0] + redbuf[1] + redbuf[2] + redbuf[3];
    q_c = redbuf[4] + redbuf[5] + redbuf[6] + redbuf[7];
  }
  const float inv1024 = 1.0f / 1024.0f;
  float mu_c = s_c * inv1024;
  float rs_c = rsqrtf(q_c * inv1024 - mu_c * mu_c + EPS);

  const size_t BH = (size_t)4096 * 1024;
#pragma unroll
  for (int i = 0; i < 4; ++i) {
    int h = t + 256 * i;
    float cy = (c_pre[i] - mu_c) * rs_c * gc[h] + bc[h];
    float hy = og[i] * tanhf(cy);
    size_t o = (size_t)b * 1024 + h;
    out[o] = hy;
    out[BH + o] = hy;
    out[2 * BH + o] = cy;
  }
}

extern "C" void kernel_launch(void* const* d_in, const int* in_sizes, int n_in,
                              void* d_out, int out_size, void* d_ws, size_t ws_size,
                              hipStream_t stream) {
  const float* input = (const float*)d_in[0];
  const float* hx    = (const float*)d_in[1];
  const float* cx    = (const float*)d_in[2];
  const float* wih   = (const float*)d_in[3];
  const float* whh   = (const float*)d_in[4];
  const float* gi    = (const float*)d_in[5];
  const float* bi    = (const float*)d_in[6];
  const float* gh    = (const float*)d_in[7];
  const float* bh    = (const float*)d_in[8];
  const float* gc    = (const float*)d_in[9];
  const float* bc    = (const float*)d_in[10];
  float* out = (float*)d_out;

  char* wsp = (char*)d_ws;
  u16* a_bf  = (u16*)(wsp);
  u16* h_bf  = (u16*)(wsp + ((size_t)8  << 20));
  u16* wi_bf = (u16*)(wsp + ((size_t)16 << 20));
  u16* wh_bf = (u16*)(wsp + ((size_t)24 << 20));
  u16* ig_bf = (u16*)(wsp + ((size_t)32 << 20));
  u16* hg_bf = (u16*)(wsp + ((size_t)64 << 20));

  const int nper = 4096 * 1024;
  dim3 cgrid(nper / 8 / 256, 4);
  cast4_f32_bf16<<<cgrid, 256, 0, stream>>>(input, hx, wih, whh,
                                            a_bf, h_bf, wi_bf, wh_bf, nper);

  gemm256_dual<<<512, 512, 0, stream>>>(a_bf, wi_bf, ig_bf,
                                        h_bf, wh_bf, hg_bf);

  lstm_epilogue<<<4096, 256, 0, stream>>>(ig_bf, hg_bf, cx,
                                          gi, bi, gh, bh, gc, bc, out);
}